// Round 3
// baseline (180.834 us; speedup 1.0000x reference)
//
#include <hip/hip_runtime.h>

#define MAX_REL 16
#define NTAB    33          // 2*MAX_REL+1
#define B       4
#define H       8
#define LQ      1024
#define DH      64
#define KLEN    1024
#define QTILE   8           // q rows per block

// One block = (b, h, 8 q-rows).
//  - stage ts[b,:] (4 KB) into LDS (the only LDS-staged input)
//  - proj[r][j] = dot(query_row, table[j]) read straight from global (L1-hot:
//    table is 8.4 KB, each q row read once per block) -> VMEM pipe, not LDS
//  - single __syncthreads, then gather + coalesced float4 stores
__global__ __launch_bounds__(256) void fused_pe_kernel(const float* __restrict__ query,
                                                       const float* __restrict__ table,
                                                       const int* __restrict__ time_ids,
                                                       float* __restrict__ out) {
    __shared__ int   ts[KLEN];             // 4 KB
    __shared__ float pr[QTILE * NTAB];     // 264 floats

    const int tid  = threadIdx.x;
    const int tile = blockIdx.x;           // 0 .. B*H*128-1
    const int bh   = tile >> 7;            // LQ/QTILE = 128 tiles per (b,h)
    const int qt   = tile & 127;
    const int b    = bh >> 3;              // H = 8
    const int q0   = qt * QTILE;
    const int rowbase = bh * LQ + q0;

    // stage ts[b, 0..1023] : 256 threads x int4
    ((int4*)ts)[tid] = ((const int4*)(time_ids + b * KLEN))[tid];

    // proj: 264 dots, operands from global/L1 (VMEM pipe)
    for (int t = tid; t < QTILE * NTAB; t += 256) {
        int r = t / NTAB;                  // const divisor -> magic mul
        int j = t - r * NTAB;
        const float4* qv = (const float4*)(query + (size_t)(rowbase + r) * DH);
        const float4* tv = (const float4*)(table + j * DH);
        float acc = 0.f;
#pragma unroll
        for (int i = 0; i < DH / 4; ++i) {
            float4 a = qv[i];
            float4 w = tv[i];
            acc += a.x * w.x + a.y * w.y + a.z * w.z + a.w * w.w;
        }
        pr[t] = acc;                       // layout [r*33 + j]
    }
    __syncthreads();

    // gather + coalesced float4 stores
    const int k0 = tid << 2;
    const int4 tk = ((const int4*)ts)[tid];
    float* op = out + (size_t)rowbase * KLEN + k0;

#pragma unroll
    for (int r = 0; r < QTILE; ++r) {
        const int tq = ts[q0 + r];         // LDS broadcast
        int i0 = min(max(tk.x - tq, -MAX_REL), MAX_REL) + MAX_REL;
        int i1 = min(max(tk.y - tq, -MAX_REL), MAX_REL) + MAX_REL;
        int i2 = min(max(tk.z - tq, -MAX_REL), MAX_REL) + MAX_REL;
        int i3 = min(max(tk.w - tq, -MAX_REL), MAX_REL) + MAX_REL;
        const float* prr = pr + r * NTAB;
        float4 v = make_float4(prr[i0], prr[i1], prr[i2], prr[i3]);
        *((float4*)op) = v;
        op += KLEN;
    }
}

extern "C" void kernel_launch(void* const* d_in, const int* in_sizes, int n_in,
                              void* d_out, int out_size, void* d_ws, size_t ws_size,
                              hipStream_t stream) {
    const float* query    = (const float*)d_in[0];   // (B,H,LQ,DH) f32
    const float* table    = (const float*)d_in[1];   // (33, DH) f32
    const int*   time_ids = (const int*)d_in[2];     // (B, KLEN) int32
    float* out = (float*)d_out;                      // (B,H,LQ,KLEN) f32

    fused_pe_kernel<<<B * H * (LQ / QTILE), 256, 0, stream>>>(query, table, time_ids, out);
}

// Round 5
// 146.469 us; speedup vs baseline: 1.2346x; 1.2346x over previous
//
#include <hip/hip_runtime.h>

#define MAX_REL 16
#define NTAB    33          // 2*MAX_REL+1
#define B       4
#define H       8
#define LQ      1024
#define DH      64
#define KLEN    1024
#define QTILE   16          // q rows per block (4 per wave)
#define TSTRIDE 68          // padded table row stride (floats)

// One block = (b, h, 16 q-rows); 4 waves, each wave owns 4 rows.
// Phase 1 (cooperative): stage ts, query tile, table into LDS; ONE barrier.
// Phase 2 (wave-private): 4x33 dots into the wave's pr slice (no barrier:
//   within-wave LDS RAW is ordered by compiler-emitted lgkmcnt waits).
// Phase 3 (wave-private): gather + coalesced float4 stores. Waves drift so
//   LDS-pipe compute of some waves hides under the store drain of others.
__global__ __launch_bounds__(256) void fused_pe_kernel(const float* __restrict__ query,
                                                       const float* __restrict__ table,
                                                       const int* __restrict__ time_ids,
                                                       float* __restrict__ out) {
    __shared__ int   ts[KLEN];                 // 4 KB
    __shared__ float qt[QTILE * DH];           // 4 KB
    __shared__ float tb[NTAB * TSTRIDE];       // 8.8 KB
    __shared__ float pr[QTILE * NTAB];         // 2.1 KB (wave w owns rows w*4..w*4+3)

    const int tid  = threadIdx.x;
    const int wave = tid >> 6;
    const int lane = tid & 63;
    const int tile = blockIdx.x;               // 0 .. B*H*64-1
    const int bh   = tile >> 6;                // 64 tiles per (b,h)
    const int qt_i = tile & 63;
    const int b    = bh >> 3;                  // H = 8
    const int q0   = qt_i * QTILE;
    const int rowbase = bh * LQ + q0;

    // ---- Phase 1: cooperative staging ----
    ((int4*)ts)[tid] = ((const int4*)(time_ids + b * KLEN))[tid];              // 4 KB
    ((float4*)qt)[tid] = ((const float4*)(query + (size_t)rowbase * DH))[tid]; // 16 rows
    for (int i = tid; i < NTAB * 16; i += 256) {                               // 33 rows
        int r = i >> 4, c = i & 15;
        ((float4*)(tb + r * TSTRIDE))[c] = ((const float4*)(table + r * DH))[c];
    }
    __syncthreads();                           // the only barrier

    // ---- Phase 2: wave-private 4x33 dots ----
    const int r0 = wave * 4;                   // first row owned by this wave
    for (int t = lane; t < 4 * NTAB; t += 64) {
        int r = t / NTAB;                      // 0..3 (const divisor -> magic mul)
        int j = t - r * NTAB;
        const float4* qv = (const float4*)(qt + (r0 + r) * DH);   // broadcast-heavy
        const float4* tv = (const float4*)(tb + j * TSTRIDE);
        float acc = 0.f;
#pragma unroll
        for (int i = 0; i < DH / 4; ++i) {
            float4 a = qv[i];
            float4 w = tv[i];
            acc += a.x * w.x + a.y * w.y + a.z * w.z + a.w * w.w;
        }
        pr[(r0 + r) * NTAB + j] = acc;
    }
    // no __syncthreads: pr slice is read only by this wave below

    // ---- Phase 3: wave-private gather + stores (4 rows x 4 chunks) ----
    const int4 tk0 = ((const int4*)ts)[0 * 64 + lane];
    const int4 tk1 = ((const int4*)ts)[1 * 64 + lane];
    const int4 tk2 = ((const int4*)ts)[2 * 64 + lane];
    const int4 tk3 = ((const int4*)ts)[3 * 64 + lane];

#pragma unroll
    for (int r = 0; r < 4; ++r) {
        const int row = r0 + r;
        const int tq  = ts[q0 + row];          // LDS broadcast
        const float* prr = pr + row * NTAB;
        float* op = out + (size_t)(rowbase + row) * KLEN + (lane << 2);
#pragma unroll
        for (int c = 0; c < 4; ++c) {
            int4 tk = (c == 0) ? tk0 : (c == 1) ? tk1 : (c == 2) ? tk2 : tk3;
            int i0 = min(max(tk.x - tq, -MAX_REL), MAX_REL) + MAX_REL;
            int i1 = min(max(tk.y - tq, -MAX_REL), MAX_REL) + MAX_REL;
            int i2 = min(max(tk.z - tq, -MAX_REL), MAX_REL) + MAX_REL;
            int i3 = min(max(tk.w - tq, -MAX_REL), MAX_REL) + MAX_REL;
            float4 v = make_float4(prr[i0], prr[i1], prr[i2], prr[i3]);
            *((float4*)(op + c * 256)) = v;
        }
    }
}

extern "C" void kernel_launch(void* const* d_in, const int* in_sizes, int n_in,
                              void* d_out, int out_size, void* d_ws, size_t ws_size,
                              hipStream_t stream) {
    const float* query    = (const float*)d_in[0];   // (B,H,LQ,DH) f32
    const float* table    = (const float*)d_in[1];   // (33, DH) f32
    const int*   time_ids = (const int*)d_in[2];     // (B, KLEN) int32
    float* out = (float*)d_out;                      // (B,H,LQ,KLEN) f32

    fused_pe_kernel<<<B * H * (LQ / QTILE), 256, 0, stream>>>(query, table, time_ids, out);
}

// Round 6
// 143.863 us; speedup vs baseline: 1.2570x; 1.0181x over previous
//
#include <hip/hip_runtime.h>

#define MAX_REL 16
#define NTAB    33          // 2*MAX_REL+1
#define B       4
#define H       8
#define LQ      1024
#define DH      64
#define KLEN    1024
#define QTILE   16          // q rows per block (4 per wave)
#define PRS     48          // pr row stride (floats)

typedef short s16x8 __attribute__((ext_vector_type(8)));   // 8 bf16 (4 VGPRs)
typedef float f32x4 __attribute__((ext_vector_type(4)));   // MFMA acc

// round-to-nearest-even f32 -> bf16
static __device__ __forceinline__ short f2bf(float f) {
    unsigned u = __float_as_uint(f);
    unsigned r = (u + 0x7FFFu + ((u >> 16) & 1u)) >> 16;
    return (short)r;
}

// One block = (b, h, 16 q-rows); 4 waves.
// Phase 1: stage ts (int), Q and T as bf16 in MFMA fragment order; one barrier.
// Phase 2 (wave-private, barrier-free): each wave computes the full 16x48
//   proj tile with 6 MFMAs (duplicated across waves; MFMA pipe is idle) and
//   writes only its own 4 rows (lanes with quad==wave hold exactly those rows
//   in the D layout: row = quad*4 + reg, col = lane&15).
// Phase 3 (wave-private): gather + coalesced float4 stores.
__global__ __launch_bounds__(256) void fused_pe_kernel(const float* __restrict__ query,
                                                       const float* __restrict__ table,
                                                       const int* __restrict__ time_ids,
                                                       float* __restrict__ out) {
    __shared__ int   ts[KLEN];               // 4 KB
    __shared__ short qth[2 * 64 * 8];        // A-frags [kstep][lane][j]   2 KB
    __shared__ short tbh[2 * 4 * 48 * 8];    // B-frags [kstep][quad][n][j] 6 KB
    __shared__ float pr[QTILE * PRS];        // 3 KB

    const int tid  = threadIdx.x;
    const int wave = tid >> 6;
    const int lane = tid & 63;
    const int tile = blockIdx.x;             // 0 .. B*H*64-1
    const int bh   = tile >> 6;
    const int qt_i = tile & 63;
    const int b    = bh >> 3;                // H = 8
    const int q0   = qt_i * QTILE;
    const int rowbase = bh * LQ + q0;

    // ---- Phase 1: staging (fragment-order bf16 conversion) ----
    ((int4*)ts)[tid] = ((const int4*)(time_ids + b * KLEN))[tid];

    {   // Q tile: element (m, 4c..4c+3) = flat float4 index tid
        float4 v = ((const float4*)(query + (size_t)rowbase * DH))[tid];
        int m = tid >> 4, c = tid & 15;
        int kstep = c >> 3, quad = (c >> 1) & 3, jb = (c & 1) << 2;
        short4 hv = make_short4(f2bf(v.x), f2bf(v.y), f2bf(v.z), f2bf(v.w));
        *(short4*)(qth + ((kstep * 64 + quad * 16 + m) << 3) + jb) = hv;
    }
    for (int i = tid; i < NTAB * 16; i += 256) {   // table rows 0..32
        int n = i >> 4, c = i & 15;
        float4 v = ((const float4*)table)[i];
        int kstep = c >> 3, quad = (c >> 1) & 3, jb = (c & 1) << 2;
        short4 hv = make_short4(f2bf(v.x), f2bf(v.y), f2bf(v.z), f2bf(v.w));
        *(short4*)(tbh + (((kstep * 4 + quad) * 48 + n) << 3) + jb) = hv;
    }
    __syncthreads();                         // the only barrier

    // ---- Phase 2: MFMA proj, wave-private writes ----
    const int quad = lane >> 4;
    const int nlo  = lane & 15;
    f32x4 acc0 = {0.f, 0.f, 0.f, 0.f}, acc1 = acc0, acc2 = acc0;
#pragma unroll
    for (int kstep = 0; kstep < 2; ++kstep) {
        s16x8 a = *(const s16x8*)(qth + ((kstep * 64 + lane) << 3));
        const short* bbase = tbh + (((kstep * 4 + quad) * 48) << 3);
        s16x8 b0 = *(const s16x8*)(bbase + (nlo << 3));
        s16x8 b1 = *(const s16x8*)(bbase + ((nlo + 16) << 3));
        s16x8 b2 = *(const s16x8*)(bbase + (32 << 3));   // n clamped to 32 (broadcast)
        acc0 = __builtin_amdgcn_mfma_f32_16x16x32_bf16(a, b0, acc0, 0, 0, 0);
        acc1 = __builtin_amdgcn_mfma_f32_16x16x32_bf16(a, b1, acc1, 0, 0, 0);
        acc2 = __builtin_amdgcn_mfma_f32_16x16x32_bf16(a, b2, acc2, 0, 0, 0);
    }
    if (quad == wave) {                      // these lanes hold rows 4*wave..4*wave+3
#pragma unroll
        for (int i = 0; i < 4; ++i) {
            int row = wave * 4 + i;
            pr[row * PRS + nlo]      = acc0[i];
            pr[row * PRS + 16 + nlo] = acc1[i];
            pr[row * PRS + 32]       = acc2[i];   // all 16 lanes write same value
        }
    }
    // no barrier: pr rows 4w..4w+3 written and read by wave w only

    // ---- Phase 3: wave-private gather + coalesced float4 stores ----
    const int4 tk0 = ((const int4*)ts)[0 * 64 + lane];
    const int4 tk1 = ((const int4*)ts)[1 * 64 + lane];
    const int4 tk2 = ((const int4*)ts)[2 * 64 + lane];
    const int4 tk3 = ((const int4*)ts)[3 * 64 + lane];

#pragma unroll
    for (int r = 0; r < 4; ++r) {
        const int row = wave * 4 + r;
        const int tq  = ts[q0 + row];        // LDS broadcast (wave-uniform)
        const float* prr = pr + row * PRS;
        float* op = out + (size_t)(rowbase + row) * KLEN + (lane << 2);
#pragma unroll
        for (int c = 0; c < 4; ++c) {
            int4 tk = (c == 0) ? tk0 : (c == 1) ? tk1 : (c == 2) ? tk2 : tk3;
            int i0 = min(max(tk.x - tq, -MAX_REL), MAX_REL) + MAX_REL;
            int i1 = min(max(tk.y - tq, -MAX_REL), MAX_REL) + MAX_REL;
            int i2 = min(max(tk.z - tq, -MAX_REL), MAX_REL) + MAX_REL;
            int i3 = min(max(tk.w - tq, -MAX_REL), MAX_REL) + MAX_REL;
            float4 v = make_float4(prr[i0], prr[i1], prr[i2], prr[i3]);
            *((float4*)(op + c * 256)) = v;
        }
    }
}

extern "C" void kernel_launch(void* const* d_in, const int* in_sizes, int n_in,
                              void* d_out, int out_size, void* d_ws, size_t ws_size,
                              hipStream_t stream) {
    const float* query    = (const float*)d_in[0];   // (B,H,LQ,DH) f32
    const float* table    = (const float*)d_in[1];   // (33, DH) f32
    const int*   time_ids = (const int*)d_in[2];     // (B, KLEN) int32
    float* out = (float*)d_out;                      // (B,H,LQ,KLEN) f32

    fused_pe_kernel<<<B * H * (LQ / QTILE), 256, 0, stream>>>(query, table, time_ids, out);
}